// Round 16
// baseline (428.733 us; speedup 1.0000x reference)
//
#include <hip/hip_runtime.h>
#include <math.h>

typedef __attribute__((ext_vector_type(4)))  int   i32x4;
typedef __attribute__((ext_vector_type(16))) int   i32x16;
typedef __attribute__((ext_vector_type(4)))  float f32x4;
typedef __attribute__((ext_vector_type(8)))  unsigned short u16x8;

#define NTOK   8192
#define DIMD   1024
#define HID    2048
#define NEXP   8
#define NPAIR  16384

// ---- workspace byte offsets ----
#define XQ_OFF      0L            // int8 [8192][1024]
#define WQIN_OFF    8388608L      // int8 packed frags [8][128 cb32][32 kb][64 lane][16]
#define WQOUT_OFF   41943040L     // int8 packed frags [8][32 cb32][64 kb][64 lane][16]
#define XG_OFF      58720256L     // int8 frag-order gathered xq (rows 512-padded/e) 20MB
#define HG_OFF      79691776L     // int8 frag-order hq (rows 512-padded/e) 40MB
#define GLUG_OFF    121634816L    // bf16 row-ordered [<=20480][2048] 80MB; reused as pout bf16 [16384][1024]
#define XRECG_OFF   205520896L    // f32 [20480] per-row x scale
#define GATE_OFF    205602816L    // f32 [16384]
#define HRECG_OFF   205668352L    // f32 [20480] per-row gate*h scale (also hosts token-indexed xrec early)
#define TLIST_OFF   205750272L    // int [8][8192]
#define CNT_OFF     206012416L    // int [8]
#define PSUM_OFF    206012448L    // f32 [8]
#define ZSUM_OFF    206012480L    // f32 [1]
#define PART_OFF    206012512L    // f32 [768]
#define WRECIN_OFF  206015616L
#define WRECOUT_OFF 206015648L
#define WSCLIN_OFF  206015680L
#define WSCLOUT_OFF 206015712L
#define OFF_OFF     206015744L    // int [8] prefix of 512-padded cnts

__device__ __forceinline__ int clampi(int v, int lo, int hi){ return v<lo?lo:(v>hi?hi:v); }

__device__ __forceinline__ unsigned packq(f32x4 v, float s, int lo, int hi){
  int q0 = clampi((int)rintf(v.x*s), lo, hi);
  int q1 = clampi((int)rintf(v.y*s), lo, hi);
  int q2 = clampi((int)rintf(v.z*s), lo, hi);
  int q3 = clampi((int)rintf(v.w*s), lo, hi);
  return (unsigned)((q0&255)|((q1&255)<<8)|((q2&255)<<16)|((q3&255)<<24));
}

__device__ __forceinline__ unsigned short f2bf(float f){
  unsigned u = __float_as_uint(f);
  u += 0x7fffu + ((u >> 16) & 1u);
  return (unsigned short)(u >> 16);
}
__device__ __forceinline__ float bf2f(unsigned short b){
  return __uint_as_float(((unsigned)b) << 16);
}

// ---------------- init ----------------
__global__ void k_init(int* __restrict__ cnts, float* __restrict__ psum, float* __restrict__ zsum){
  int i = threadIdx.x;
  if (i < 8){ cnts[i]=0; psum[i]=0.f; }
  if (i == 8) zsum[0]=0.f;
}

// ---------------- router + act_quant(x) ----------------
__global__ __launch_bounds__(1024) void k_router(
    const float* __restrict__ x, const float* __restrict__ wg,
    signed char* __restrict__ xq, float* __restrict__ xrec,
    float* __restrict__ gatep, int* __restrict__ tlist, int* __restrict__ cnts,
    float* __restrict__ psum, float* __restrict__ zsum)
{
  __shared__ float ls_p[8]; __shared__ float ls_z[1];
  __shared__ int ls_c[8];  __shared__ int ls_b[8];
  int tid = threadIdx.x;
  if (tid<8){ ls_p[tid]=0.f; ls_c[tid]=0; }
  if (tid==8) ls_z[0]=0.f;
  __syncthreads();
  int wave = tid>>6, lane = tid&63;
  int tok = blockIdx.x*16 + wave;

  const f32x4* x4 = (const f32x4*)(x + (long)tok*DIMD) + lane*4;
  f32x4 xv[4];
  #pragma unroll
  for (int j=0;j<4;++j) xv[j] = x4[j];

  float amax = 0.f;
  float lg[8] = {0,0,0,0,0,0,0,0};
  const f32x4* wg4 = (const f32x4*)wg;
  #pragma unroll
  for (int j=0;j<16;++j){
    float xd = xv[j>>2][j&3];
    amax = fmaxf(amax, fabsf(xd));
    int d = lane*16 + j;
    f32x4 w0 = wg4[d*2], w1 = wg4[d*2+1];
    lg[0]+=xd*w0.x; lg[1]+=xd*w0.y; lg[2]+=xd*w0.z; lg[3]+=xd*w0.w;
    lg[4]+=xd*w1.x; lg[5]+=xd*w1.y; lg[6]+=xd*w1.z; lg[7]+=xd*w1.w;
  }
  for (int m=1;m<64;m<<=1){
    amax = fmaxf(amax, __shfl_xor(amax, m));
    #pragma unroll
    for (int e=0;e<8;++e) lg[e] += __shfl_xor(lg[e], m);
  }
  float cm = fmaxf(amax, 1e-5f);
  float sx = 127.f/cm;
  unsigned p0 = packq(xv[0], sx, -128, 127);
  unsigned p1 = packq(xv[1], sx, -128, 127);
  unsigned p2 = packq(xv[2], sx, -128, 127);
  unsigned p3 = packq(xv[3], sx, -128, 127);
  i32x4 pk; pk.x=(int)p0; pk.y=(int)p1; pk.z=(int)p2; pk.w=(int)p3;
  *(i32x4*)(xq + (long)tok*DIMD + lane*16) = pk;

  int e1=0, e2=0, s1=0, s2=0;
  if (lane==0){
    xrec[tok] = cm*(1.f/127.f);
    e1 = 0;
    for (int e=1;e<8;++e) if (lg[e] > lg[e1]) e1 = e;
    e2 = (e1==0)?1:0;
    for (int e=0;e<8;++e) if (e!=e1 && lg[e] > lg[e2]) e2 = e;
    float t = expf(lg[e2]-lg[e1]);
    gatep[tok*2]   = 1.f/(1.f+t);
    gatep[tok*2+1] = t/(1.f+t);
    float mx = lg[e1], sum = 0.f, pr[8];
    #pragma unroll
    for (int e=0;e<8;++e){ pr[e] = expf(lg[e]-mx); sum += pr[e]; }
    float inv = 1.f/sum;
    #pragma unroll
    for (int e=0;e<8;++e) atomicAdd(&ls_p[e], pr[e]*inv);
    float lse = mx + logf(sum);
    atomicAdd(&ls_z[0], lse*lse);
    s1 = atomicAdd(&ls_c[e1], 1);
    s2 = atomicAdd(&ls_c[e2], 1);
  }
  __syncthreads();
  if (tid<8) ls_b[tid] = atomicAdd(&cnts[tid], ls_c[tid]);
  __syncthreads();
  if (lane==0){
    tlist[e1*NTOK + ls_b[e1] + s1] = tok*2;
    tlist[e2*NTOK + ls_b[e2] + s2] = tok*2 + 1;
  }
  if (tid<8)  atomicAdd(&psum[tid], ls_p[tid]);
  if (tid==8) atomicAdd(zsum, ls_z[0]);
}

// ---------------- weight |w| partial sums ----------------
__global__ void k_wabs(const float* __restrict__ w_in, const float* __restrict__ w_out,
                       float* __restrict__ part){
  int b = blockIdx.x, tid = threadIdx.x;
  const float* base = (b < 512) ? (w_in + (long)b*65536) : (w_out + (long)(b-512)*65536);
  const f32x4* p4 = (const f32x4*)base;
  float s = 0.f;
  for (int i = tid; i < 16384; i += 256){
    f32x4 v = p4[i];
    s += fabsf(v.x)+fabsf(v.y)+fabsf(v.z)+fabsf(v.w);
  }
  __shared__ float red[256];
  red[tid] = s; __syncthreads();
  for (int off=128; off; off>>=1){ if (tid<off) red[tid]+=red[tid+off]; __syncthreads(); }
  if (tid==0) part[b] = red[0];
}

// ---------------- wmean + expert row-offset prefix (512-padded) ----------------
__global__ void k_wmean(const float* __restrict__ part, const int* __restrict__ cnts,
                        float* __restrict__ wrec_in, float* __restrict__ wrec_out,
                        float* __restrict__ wscl_in, float* __restrict__ wscl_out,
                        int* __restrict__ off){
  int t = threadIdx.x;
  if (t < 8){
    float s = 0.f;
    for (int i=0;i<64;++i) s += part[t*64+i];
    float cmm = fmaxf(s/4194304.f, 1e-5f);
    wrec_in[t] = cmm; wscl_in[t] = 1.f/cmm;
  } else if (t < 16){
    int e = t-8; float s = 0.f;
    for (int i=0;i<32;++i) s += part[512 + e*32 + i];
    float cmm = fmaxf(s/2097152.f, 1e-5f);
    wrec_out[e] = cmm; wscl_out[e] = 1.f/cmm;
  } else if (t == 16){
    int acc = 0;
    for (int e=0;e<8;++e){ off[e] = acc; acc += (cnts[e] + 511) & ~511; }
  }
}

// ---------------- ternarize + pack weights into 32x32x32 MFMA fragment order ----------------
__global__ void k_packw(const float* __restrict__ w, i32x4* __restrict__ wq,
                        const float* __restrict__ wscl, int COLS, int K, int KB,
                        long chunksPerE){
  long t = (long)blockIdx.x*blockDim.x + threadIdx.x;
  int e = (int)(t / chunksPerE);
  long r = t - (long)e*chunksPerE;
  int lane = (int)(r & 63);
  long fb = r >> 6;
  int kb = (int)(fb % KB);
  int cb = (int)(fb / KB);
  int col = cb*32 + (lane & 31);
  int k0  = kb*32 + (lane >> 5)*16;
  const f32x4* src = (const f32x4*)(w + ((long)e*COLS + col)*K + k0);
  float s = wscl[e];
  f32x4 v0 = src[0], v1 = src[1], v2 = src[2], v3 = src[3];
  i32x4 o;
  o.x = (int)packq(v0, s, -1, 1);
  o.y = (int)packq(v1, s, -1, 1);
  o.z = (int)packq(v2, s, -1, 1);
  o.w = (int)packq(v3, s, -1, 1);
  wq[t] = o;
}

// ---------------- gather xq rows into per-expert frag-order A buffer + xrec_g ----------------
__global__ void k_gatherx(const signed char* __restrict__ xq, const int* __restrict__ tlist,
                          const int* __restrict__ cnts, const int* __restrict__ off,
                          const float* __restrict__ xrec,
                          signed char* __restrict__ xg, float* __restrict__ xrecg){
  int e = blockIdx.x & 7;
  int cnt = cnts[e];
  int w = threadIdx.x >> 6;
  int c = threadIdx.x & 63;
  int goff = off[e];
  signed char* xb = xg + (long)goff*1024;
  for (int r = (blockIdx.x>>3)*4 + w; r < cnt; r += 2048){
    int pr = tlist[e*NTOK + r];
    if (c == 0) xrecg[goff + r] = xrec[pr>>1];
    i32x4 v = *(const i32x4*)(xq + (long)(pr>>1)*DIMD + c*16);
    int kb = c>>1, lhi = c&1;
    *(i32x4*)(xb + ((long)(r>>5)*32 + kb)*1024 + (lhi*32 + (r&31))*16) = v;
  }
}

#define MF(A,B,C) C = __builtin_amdgcn_mfma_i32_32x32x32_i8(A,B,C,0,0,0)

// ---------------- GEMM1: 128 h-cols (64 h1 + 64 g) in 128KB dyn LDS ----------------
// grid 256: e = blk&7 (XCD-lock), ct = blk>>3 (0..31). 16 waves x 32 rows = 512 rows/iter.
// wave = 32 rows x 128 cols: acc 4x i32x16 (64), A 1 frag e/o, B 4 frags e/o.
// A-bytes/MFMA halved vs 64-col variant at iso-occupancy (16 waves/CU).
__global__ __launch_bounds__(1024, 4) void k_gemm1(
    const signed char* __restrict__ xg, const signed char* __restrict__ wqin,
    const int* __restrict__ cnts, const int* __restrict__ off,
    const float* __restrict__ xrecg_all, const float* __restrict__ wrec_in,
    unsigned short* __restrict__ glug_all)
{
  extern __shared__ signed char bsh[];     // 128KB: 4 planes x 32KB (h1cf0,h1cf1,gcf0,gcf1)
  const int e = blockIdx.x & 7;
  const int ct = blockIdx.x >> 3;
  const int cnt = cnts[e];
  const int tid = threadIdx.x;
  const int goff = off[e];
  {
    const long eb = (long)e*4194304;
    const i32x4* s0 = (const i32x4*)(wqin + eb + (long)(ct*2      )*32768);
    const i32x4* s1 = (const i32x4*)(wqin + eb + (long)(ct*2 +  1 )*32768);
    const i32x4* s2 = (const i32x4*)(wqin + eb + (long)(ct*2 + 64 )*32768);
    const i32x4* s3 = (const i32x4*)(wqin + eb + (long)(ct*2 + 65 )*32768);
    i32x4* d = (i32x4*)bsh;
    d[tid]        = s0[tid]; d[tid+1024]        = s0[tid+1024];
    d[2048 + tid] = s1[tid]; d[2048 + tid+1024] = s1[tid+1024];
    d[4096 + tid] = s2[tid]; d[4096 + tid+1024] = s2[tid+1024];
    d[6144 + tid] = s3[tid]; d[6144 + tid+1024] = s3[tid+1024];
  }
  __syncthreads();

  const int wave = tid>>6, lane = tid&63, l31 = lane&31, lhi = lane>>5;
  const float wr = wrec_in[e];
  const float* xrecg = xrecg_all + goff;
  unsigned short* glug = glug_all + (long)goff*HID;
  const signed char* xbase = xg + (long)goff*1024;
  const signed char* lb = bsh + lane*16;
  const int maxit = (cnt + 511) >> 9;

  #pragma unroll 1
  for (int it=0; it<maxit; ++it){
    const int rb = it*512 + wave*32;
    const i32x4* a0 = (const i32x4*)(xbase + (long)(rb>>5)*32768) + lane;

    i32x16 p0=(i32x16)0, p1=(i32x16)0, q0=(i32x16)0, q1=(i32x16)0;
    i32x4 eA=a0[0], oA=a0[64];
    i32x4 eB0=*(const i32x4*)(lb),       eB1=*(const i32x4*)(lb+32768);
    i32x4 eB2=*(const i32x4*)(lb+65536), eB3=*(const i32x4*)(lb+98304);
    i32x4 oB0=*(const i32x4*)(lb+1024),       oB1=*(const i32x4*)(lb+32768+1024);
    i32x4 oB2=*(const i32x4*)(lb+65536+1024), oB3=*(const i32x4*)(lb+98304+1024);
    #pragma unroll 1
    for (int kb=0; kb<30; kb+=2){
      a0 += 128;
      MF(eA,eB0,p0); MF(eA,eB1,p1); MF(eA,eB2,q0); MF(eA,eB3,q1);
      eA = a0[0];
      eB0=*(const i32x4*)(lb + (kb+2)*1024);
      eB1=*(const i32x4*)(lb + 32768 + (kb+2)*1024);
      eB2=*(const i32x4*)(lb + 65536 + (kb+2)*1024);
      eB3=*(const i32x4*)(lb + 98304 + (kb+2)*1024);
      MF(oA,oB0,p0); MF(oA,oB1,p1); MF(oA,oB2,q0); MF(oA,oB3,q1);
      oA = a0[64];
      oB0=*(const i32x4*)(lb + (kb+3)*1024);
      oB1=*(const i32x4*)(lb + 32768 + (kb+3)*1024);
      oB2=*(const i32x4*)(lb + 65536 + (kb+3)*1024);
      oB3=*(const i32x4*)(lb + 98304 + (kb+3)*1024);
    }
    MF(eA,eB0,p0); MF(eA,eB1,p1); MF(eA,eB2,q0); MF(eA,eB3,q1);
    MF(oA,oB0,p0); MF(oA,oB1,p1); MF(oA,oB2,q0); MF(oA,oB3,q1);

#define GLUEPI(P,Q,CO) { \
    _Pragma("unroll") \
    for (int g=0; g<16; ++g){ \
      int r = rb + (g&3) + 8*(g>>2) + 4*lhi; \
      if (r < cnt){ \
        float dq = xrecg[r]*wr; \
        float h1 = (float)P[g]*dq; \
        float gg = (float)Q[g]*dq; \
        float t = __expf(-h1); \
        float v = h1*gg*__builtin_amdgcn_rcpf(1.f+t); \
        glug[(long)r*HID + ct*64 + (CO) + l31] = f2bf(v); \
      } \
    } }
    GLUEPI(p0,q0,0)
    GLUEPI(p1,q1,32)
#undef GLUEPI
  }
}

// ---------------- act_quant(glu row) -> hg frag-order + hrec_g (gate folded) ----------------
__global__ __launch_bounds__(256) void k_quanthg(
    const unsigned short* __restrict__ glug, const int* __restrict__ tlist,
    const int* __restrict__ cnts, const int* __restrict__ off,
    const float* __restrict__ gatep, signed char* __restrict__ hg, float* __restrict__ hrecg){
  int e = blockIdx.x & 7;
  int cnt = cnts[e];
  const int wv = threadIdx.x>>6, lane = threadIdx.x&63;
  int r = (blockIdx.x>>3)*4 + wv;
  if (r >= cnt) return;
  const int* tl = tlist + e*NTOK;
  int goff = off[e];
  signed char* hb = hg + (long)goff*2048;
  const unsigned short* row = glug + (long)(goff+r)*HID;

  u16x8 v0 = *(const u16x8*)(row + lane*8);
  u16x8 v1 = *(const u16x8*)(row + 512 + lane*8);
  u16x8 v2 = *(const u16x8*)(row + 1024 + lane*8);
  u16x8 v3 = *(const u16x8*)(row + 1536 + lane*8);
  float m = 0.f;
  #pragma unroll
  for (int j=0;j<8;++j){
    m = fmaxf(m, fmaxf(fmaxf(fabsf(bf2f(v0[j])), fabsf(bf2f(v1[j]))),
                       fmaxf(fabsf(bf2f(v2[j])), fabsf(bf2f(v3[j])))));
  }
  #pragma unroll
  for (int mm=1; mm<64; mm<<=1) m = fmaxf(m, __shfl_xor(m, mm));
  float cmm = fmaxf(m, 1e-5f);
  if (lane == 0) hrecg[goff + r] = gatep[tl[r]] * cmm * (1.f/127.f);
  float s = 127.f/cmm;

#define QCHUNK(V, CIDX) { \
    f32x4 a, b; \
    a.x=bf2f(V[0]); a.y=bf2f(V[1]); a.z=bf2f(V[2]); a.w=bf2f(V[3]); \
    b.x=bf2f(V[4]); b.y=bf2f(V[5]); b.z=bf2f(V[6]); b.w=bf2f(V[7]); \
    uint2 u; u.x = packq(a, s, -128, 127); u.y = packq(b, s, -128, 127); \
    int c = (CIDX); \
    int kb = c>>2, lhi = (c>>1)&1, h = c&1; \
    *(uint2*)(hb + ((long)(r>>5)*64 + kb)*1024 + (lhi*32 + (r&31))*16 + h*8) = u; \
  }
  QCHUNK(v0, lane)
  QCHUNK(v1, lane+64)
  QCHUNK(v2, lane+128)
  QCHUNK(v3, lane+192)
#undef QCHUNK
}

// ---------------- GEMM2: 64 dcols in 128KB dyn LDS, A frag-order from hg; bf16 pout ----------------
// grid 256: e = blk&7, ct = (blk>>3)&15, rh = blk>>7. 16 waves x 64 rows = 1024 rows/iter.
// wave = 64 rows x 64 cols: acc 4x i32x16, A 2 frags e/o, B 2 frags e/o.
__global__ __launch_bounds__(1024, 4) void k_gemm2(
    const signed char* __restrict__ hg, const signed char* __restrict__ wqout,
    const int* __restrict__ tlist, const int* __restrict__ cnts, const int* __restrict__ off,
    const float* __restrict__ hrecg_all, const float* __restrict__ wrec_out,
    unsigned short* __restrict__ pout)
{
  extern __shared__ signed char bsh[];     // 128KB: 2 planes x 64KB (cf0, cf1)
  const int e = blockIdx.x & 7;
  const int ct = (blockIdx.x >> 3) & 15;
  const int rh = blockIdx.x >> 7;
  const int cnt = cnts[e];
  const int tid = threadIdx.x;
  const int goff = off[e];
  {
    const long eb = (long)e*2097152;
    const i32x4* s0 = (const i32x4*)(wqout + eb + (long)(ct*2    )*65536);
    const i32x4* s1 = (const i32x4*)(wqout + eb + (long)(ct*2 + 1)*65536);
    i32x4* d = (i32x4*)bsh;
    #pragma unroll
    for (int i=0;i<4;++i){
      d[tid + i*1024]        = s0[tid + i*1024];
      d[4096 + tid + i*1024] = s1[tid + i*1024];
    }
  }
  __syncthreads();

  const int wave = tid>>6, lane = tid&63, l31 = lane&31, lhi = lane>>5;
  const int* tl = tlist + e*NTOK;
  const float wr = wrec_out[e];
  const float* hrecg = hrecg_all + goff;
  const signed char* hbase = hg + (long)goff*2048;
  const signed char* lb = bsh + lane*16;
  const int maxit = (cnt + 1023) >> 10;

  #pragma unroll 1
  for (int it=rh; it<maxit; it+=2){
    const int rb = it*1024 + wave*64;
    const i32x4* a0 = (const i32x4*)(hbase + (long)(rb>>5)*65536) + lane;
    const i32x4* a1 = a0 + 4096;

    i32x16 c00=(i32x16)0, c01=(i32x16)0, c10=(i32x16)0, c11=(i32x16)0;
    i32x4 eA0=a0[0], eA1=a1[0];
    i32x4 oA0=a0[64], oA1=a1[64];
    i32x4 eB0=*(const i32x4*)(lb),      eB1=*(const i32x4*)(lb+65536);
    i32x4 oB0=*(const i32x4*)(lb+1024), oB1=*(const i32x4*)(lb+65536+1024);
    #pragma unroll 1
    for (int kb=0; kb<62; kb+=2){
      a0+=128; a1+=128;
      MF(eA0,eB0,c00); MF(eA0,eB1,c01); MF(eA1,eB0,c10); MF(eA1,eB1,c11);
      eA0=a0[0]; eA1=a1[0];
      eB0=*(const i32x4*)(lb + (kb+2)*1024);
      eB1=*(const i32x4*)(lb + 65536 + (kb+2)*1024);
      MF(oA0,oB0,c00); MF(oA0,oB1,c01); MF(oA1,oB0,c10); MF(oA1,oB1,c11);
      oA0=a0[64]; oA1=a1[64];
      oB0=*(const i32x4*)(lb + (kb+3)*1024);
      oB1=*(const i32x4*)(lb + 65536 + (kb+3)*1024);
    }
    MF(eA0,eB0,c00); MF(eA0,eB1,c01); MF(eA1,eB0,c10); MF(eA1,eB1,c11);
    MF(oA0,oB0,c00); MF(oA0,oB1,c01); MF(oA1,oB0,c10); MF(oA1,oB1,c11);

#define OUTEPI(C,RO,CO) { \
    _Pragma("unroll") \
    for (int g=0; g<16; ++g){ \
      int r = rb + (RO) + (g&3) + 8*(g>>2) + 4*lhi; \
      if (r < cnt){ \
        int pr = tl[r]; \
        float f = hrecg[r]*wr; \
        pout[(long)pr*DIMD + ct*64 + (CO) + l31] = f2bf((float)C[g]*f); \
      } \
    } }
    OUTEPI(c00,0,0)
    OUTEPI(c01,0,32)
    OUTEPI(c10,32,0)
    OUTEPI(c11,32,32)
#undef OUTEPI
  }
}

// ---------------- combine: y = bias + pout[2t] + pout[2t+1] (bf16 pout) ----------------
__global__ void k_combine(const unsigned short* __restrict__ pout, const float* __restrict__ bias,
                          float* __restrict__ y){
  long idx = (long)blockIdx.x*blockDim.x + threadIdx.x;   // over NTOK*DIMD/8
  int tok = (int)(idx >> 7);
  int c8  = (int)(idx & 127);
  u16x8 pa = ((const u16x8*)(pout + (long)tok*2*DIMD))[c8];
  u16x8 pb = ((const u16x8*)(pout + (long)tok*2*DIMD + DIMD))[c8];
  const f32x4* b4 = (const f32x4*)(bias) + c8*2;
  f32x4 b0 = b4[0], b1 = b4[1];
  f32x4 r0, r1;
  r0.x = b0.x + bf2f(pa[0]) + bf2f(pb[0]);
  r0.y = b0.y + bf2f(pa[1]) + bf2f(pb[1]);
  r0.z = b0.z + bf2f(pa[2]) + bf2f(pb[2]);
  r0.w = b0.w + bf2f(pa[3]) + bf2f(pb[3]);
  r1.x = b1.x + bf2f(pa[4]) + bf2f(pb[4]);
  r1.y = b1.y + bf2f(pa[5]) + bf2f(pb[5]);
  r1.z = b1.z + bf2f(pa[6]) + bf2f(pb[6]);
  r1.w = b1.w + bf2f(pa[7]) + bf2f(pb[7]);
  f32x4* yp = (f32x4*)(y + (long)tok*DIMD) + c8*2;
  yp[0] = r0; yp[1] = r1;
}

// ---------------- loss ----------------
__global__ void k_loss(const int* __restrict__ cnts, const float* __restrict__ psum,
                       const float* __restrict__ zsum, float* __restrict__ out){
  if (threadIdx.x==0 && blockIdx.x==0){
    float sp=0.f, sf=0.f, sw=0.f;
    for (int e=0;e<8;++e){
      float f = (float)cnts[e];
      sp += psum[e]; sf += f; sw += psum[e]*f;
    }
    float loss = 8.f*sw/(sp*sf) + 0.1f*zsum[0]/(float)NTOK;
    out[(long)NTOK*DIMD] = loss;
  }
}

extern "C" void kernel_launch(void* const* d_in, const int* in_sizes, int n_in,
                              void* d_out, int out_size, void* d_ws, size_t ws_size,
                              hipStream_t stream){
  const float* x     = (const float*)d_in[0];
  const float* wg    = (const float*)d_in[1];
  const float* w_in  = (const float*)d_in[2];
  const float* w_out = (const float*)d_in[3];
  const float* bias  = (const float*)d_in[4];
  float* y = (float*)d_out;
  char* ws = (char*)d_ws;

  signed char* xq    = (signed char*)(ws + XQ_OFF);
  signed char* wqin  = (signed char*)(ws + WQIN_OFF);
  signed char* wqout = (signed char*)(ws + WQOUT_OFF);
  signed char* xg    = (signed char*)(ws + XG_OFF);
  signed char* hg    = (signed char*)(ws + HG_OFF);
  unsigned short* glug = (unsigned short*)(ws + GLUG_OFF);
  unsigned short* pout = (unsigned short*)(ws + GLUG_OFF);  // reuse: glug dead after k_quanthg
  float* xrecg = (float*)(ws + XRECG_OFF);
  float* gatep = (float*)(ws + GATE_OFF);
  float* hrecg = (float*)(ws + HRECG_OFF);
  int* tlist = (int*)(ws + TLIST_OFF);
  int* cnts  = (int*)(ws + CNT_OFF);
  float* psum = (float*)(ws + PSUM_OFF);
  float* zsum = (float*)(ws + ZSUM_OFF);
  float* part = (float*)(ws + PART_OFF);
  float* wrec_in  = (float*)(ws + WRECIN_OFF);
  float* wrec_out = (float*)(ws + WRECOUT_OFF);
  float* wscl_in  = (float*)(ws + WSCLIN_OFF);
  float* wscl_out = (float*)(ws + WSCLOUT_OFF);
  int* offe = (int*)(ws + OFF_OFF);

  // token-indexed xrec lives in the HRECG region early (hrecg proper is written later by k_quanthg,
  // after k_gatherx has consumed xrec -> safe temporal reuse).
  float* xrec = (float*)(ws + HRECG_OFF);

  // allow 128KB dynamic LDS for the two GEMMs (host-side attr, graph-capture safe)
  hipFuncSetAttribute((const void*)k_gemm1, hipFuncAttributeMaxDynamicSharedMemorySize, 131072);
  hipFuncSetAttribute((const void*)k_gemm2, hipFuncAttributeMaxDynamicSharedMemorySize, 131072);

  k_init  <<<1, 64, 0, stream>>>(cnts, psum, zsum);
  k_router<<<512, 1024, 0, stream>>>(x, wg, xq, xrec, gatep, tlist, cnts, psum, zsum);
  k_wabs  <<<768, 256, 0, stream>>>(w_in, w_out, part);
  k_wmean <<<1, 64, 0, stream>>>(part, cnts, wrec_in, wrec_out, wscl_in, wscl_out, offe);
  k_packw <<<8192, 256, 0, stream>>>(w_in,  (i32x4*)wqin,  wscl_in,  4096, 1024, 32, 262144L);
  k_packw <<<4096, 256, 0, stream>>>(w_out, (i32x4*)wqout, wscl_out, 1024, 2048, 64, 131072L);
  k_gatherx<<<4096, 256, 0, stream>>>(xq, tlist, cnts, offe, xrec, xg, xrecg);
  k_gemm1 <<<256, 1024, 131072, stream>>>(xg, wqin, cnts, offe, xrecg, wrec_in, glug);
  k_quanthg<<<16384, 256, 0, stream>>>(glug, tlist, cnts, offe, gatep, hg, hrecg);
  k_gemm2 <<<256, 1024, 131072, stream>>>(hg, wqout, tlist, cnts, offe, hrecg, wrec_out, pout);
  k_combine<<<4096, 256, 0, stream>>>(pout, bias, y);
  k_loss  <<<1, 64, 0, stream>>>(cnts, psum, zsum, y);
}

// Round 17
// 392.811 us; speedup vs baseline: 1.0914x; 1.0914x over previous
//
#include <hip/hip_runtime.h>
#include <math.h>

typedef __attribute__((ext_vector_type(4)))  int   i32x4;
typedef __attribute__((ext_vector_type(16))) int   i32x16;
typedef __attribute__((ext_vector_type(4)))  float f32x4;
typedef __attribute__((ext_vector_type(8)))  unsigned short u16x8;

#define NTOK   8192
#define DIMD   1024
#define HID    2048
#define NEXP   8
#define NPAIR  16384

// ---- workspace byte offsets ----
#define XQ_OFF      0L            // int8 [8192][1024]
#define WQIN_OFF    8388608L      // int8 packed frags [8][128 cb32][32 kb][64 lane][16]
#define WQOUT_OFF   41943040L     // int8 packed frags [8][32 cb32][64 kb][64 lane][16]
#define XG_OFF      58720256L     // int8 frag-order gathered xq (rows 512-padded/e) 20MB
#define HG_OFF      79691776L     // int8 frag-order hq (rows 512-padded/e) 40MB
#define GLUG_OFF    121634816L    // bf16 row-ordered [<=20480][2048] 80MB; reused as pout bf16 [16384][1024]
#define XRECG_OFF   205520896L    // f32 [20480] per-row x scale
#define GATE_OFF    205602816L    // f32 [16384]
#define HRECG_OFF   205668352L    // f32 [20480] per-row gate*h scale (also hosts token-indexed xrec early)
#define TLIST_OFF   205750272L    // int [8][8192]
#define CNT_OFF     206012416L    // int [8]
#define PSUM_OFF    206012448L    // f32 [8]
#define ZSUM_OFF    206012480L    // f32 [1]
#define PART_OFF    206012512L    // f32 [768]
#define WRECIN_OFF  206015616L
#define WRECOUT_OFF 206015648L
#define WSCLIN_OFF  206015680L
#define WSCLOUT_OFF 206015712L
#define OFF_OFF     206015744L    // int [8] prefix of 512-padded cnts

__device__ __forceinline__ int clampi(int v, int lo, int hi){ return v<lo?lo:(v>hi?hi:v); }

__device__ __forceinline__ unsigned packq(f32x4 v, float s, int lo, int hi){
  int q0 = clampi((int)rintf(v.x*s), lo, hi);
  int q1 = clampi((int)rintf(v.y*s), lo, hi);
  int q2 = clampi((int)rintf(v.z*s), lo, hi);
  int q3 = clampi((int)rintf(v.w*s), lo, hi);
  return (unsigned)((q0&255)|((q1&255)<<8)|((q2&255)<<16)|((q3&255)<<24));
}

__device__ __forceinline__ unsigned short f2bf(float f){
  unsigned u = __float_as_uint(f);
  u += 0x7fffu + ((u >> 16) & 1u);
  return (unsigned short)(u >> 16);
}
__device__ __forceinline__ float bf2f(unsigned short b){
  return __uint_as_float(((unsigned)b) << 16);
}

// ---------------- init ----------------
__global__ void k_init(int* __restrict__ cnts, float* __restrict__ psum, float* __restrict__ zsum){
  int i = threadIdx.x;
  if (i < 8){ cnts[i]=0; psum[i]=0.f; }
  if (i == 8) zsum[0]=0.f;
}

// ---------------- router + act_quant(x) ----------------
__global__ __launch_bounds__(1024) void k_router(
    const float* __restrict__ x, const float* __restrict__ wg,
    signed char* __restrict__ xq, float* __restrict__ xrec,
    float* __restrict__ gatep, int* __restrict__ tlist, int* __restrict__ cnts,
    float* __restrict__ psum, float* __restrict__ zsum)
{
  __shared__ float ls_p[8]; __shared__ float ls_z[1];
  __shared__ int ls_c[8];  __shared__ int ls_b[8];
  int tid = threadIdx.x;
  if (tid<8){ ls_p[tid]=0.f; ls_c[tid]=0; }
  if (tid==8) ls_z[0]=0.f;
  __syncthreads();
  int wave = tid>>6, lane = tid&63;
  int tok = blockIdx.x*16 + wave;

  const f32x4* x4 = (const f32x4*)(x + (long)tok*DIMD) + lane*4;
  f32x4 xv[4];
  #pragma unroll
  for (int j=0;j<4;++j) xv[j] = x4[j];

  float amax = 0.f;
  float lg[8] = {0,0,0,0,0,0,0,0};
  const f32x4* wg4 = (const f32x4*)wg;
  #pragma unroll
  for (int j=0;j<16;++j){
    float xd = xv[j>>2][j&3];
    amax = fmaxf(amax, fabsf(xd));
    int d = lane*16 + j;
    f32x4 w0 = wg4[d*2], w1 = wg4[d*2+1];
    lg[0]+=xd*w0.x; lg[1]+=xd*w0.y; lg[2]+=xd*w0.z; lg[3]+=xd*w0.w;
    lg[4]+=xd*w1.x; lg[5]+=xd*w1.y; lg[6]+=xd*w1.z; lg[7]+=xd*w1.w;
  }
  for (int m=1;m<64;m<<=1){
    amax = fmaxf(amax, __shfl_xor(amax, m));
    #pragma unroll
    for (int e=0;e<8;++e) lg[e] += __shfl_xor(lg[e], m);
  }
  float cm = fmaxf(amax, 1e-5f);
  float sx = 127.f/cm;
  unsigned p0 = packq(xv[0], sx, -128, 127);
  unsigned p1 = packq(xv[1], sx, -128, 127);
  unsigned p2 = packq(xv[2], sx, -128, 127);
  unsigned p3 = packq(xv[3], sx, -128, 127);
  i32x4 pk; pk.x=(int)p0; pk.y=(int)p1; pk.z=(int)p2; pk.w=(int)p3;
  *(i32x4*)(xq + (long)tok*DIMD + lane*16) = pk;

  int e1=0, e2=0, s1=0, s2=0;
  if (lane==0){
    xrec[tok] = cm*(1.f/127.f);
    e1 = 0;
    for (int e=1;e<8;++e) if (lg[e] > lg[e1]) e1 = e;
    e2 = (e1==0)?1:0;
    for (int e=0;e<8;++e) if (e!=e1 && lg[e] > lg[e2]) e2 = e;
    float t = expf(lg[e2]-lg[e1]);
    gatep[tok*2]   = 1.f/(1.f+t);
    gatep[tok*2+1] = t/(1.f+t);
    float mx = lg[e1], sum = 0.f, pr[8];
    #pragma unroll
    for (int e=0;e<8;++e){ pr[e] = expf(lg[e]-mx); sum += pr[e]; }
    float inv = 1.f/sum;
    #pragma unroll
    for (int e=0;e<8;++e) atomicAdd(&ls_p[e], pr[e]*inv);
    float lse = mx + logf(sum);
    atomicAdd(&ls_z[0], lse*lse);
    s1 = atomicAdd(&ls_c[e1], 1);
    s2 = atomicAdd(&ls_c[e2], 1);
  }
  __syncthreads();
  if (tid<8) ls_b[tid] = atomicAdd(&cnts[tid], ls_c[tid]);
  __syncthreads();
  if (lane==0){
    tlist[e1*NTOK + ls_b[e1] + s1] = tok*2;
    tlist[e2*NTOK + ls_b[e2] + s2] = tok*2 + 1;
  }
  if (tid<8)  atomicAdd(&psum[tid], ls_p[tid]);
  if (tid==8) atomicAdd(zsum, ls_z[0]);
}

// ---------------- weight |w| partial sums ----------------
__global__ void k_wabs(const float* __restrict__ w_in, const float* __restrict__ w_out,
                       float* __restrict__ part){
  int b = blockIdx.x, tid = threadIdx.x;
  const float* base = (b < 512) ? (w_in + (long)b*65536) : (w_out + (long)(b-512)*65536);
  const f32x4* p4 = (const f32x4*)base;
  float s = 0.f;
  for (int i = tid; i < 16384; i += 256){
    f32x4 v = p4[i];
    s += fabsf(v.x)+fabsf(v.y)+fabsf(v.z)+fabsf(v.w);
  }
  __shared__ float red[256];
  red[tid] = s; __syncthreads();
  for (int off=128; off; off>>=1){ if (tid<off) red[tid]+=red[tid+off]; __syncthreads(); }
  if (tid==0) part[b] = red[0];
}

// ---------------- wmean + expert row-offset prefix (512-padded) ----------------
__global__ void k_wmean(const float* __restrict__ part, const int* __restrict__ cnts,
                        float* __restrict__ wrec_in, float* __restrict__ wrec_out,
                        float* __restrict__ wscl_in, float* __restrict__ wscl_out,
                        int* __restrict__ off){
  int t = threadIdx.x;
  if (t < 8){
    float s = 0.f;
    for (int i=0;i<64;++i) s += part[t*64+i];
    float cmm = fmaxf(s/4194304.f, 1e-5f);
    wrec_in[t] = cmm; wscl_in[t] = 1.f/cmm;
  } else if (t < 16){
    int e = t-8; float s = 0.f;
    for (int i=0;i<32;++i) s += part[512 + e*32 + i];
    float cmm = fmaxf(s/2097152.f, 1e-5f);
    wrec_out[e] = cmm; wscl_out[e] = 1.f/cmm;
  } else if (t == 16){
    int acc = 0;
    for (int e=0;e<8;++e){ off[e] = acc; acc += (cnts[e] + 511) & ~511; }
  }
}

// ---------------- ternarize + pack weights into 32x32x32 MFMA fragment order ----------------
__global__ void k_packw(const float* __restrict__ w, i32x4* __restrict__ wq,
                        const float* __restrict__ wscl, int COLS, int K, int KB,
                        long chunksPerE){
  long t = (long)blockIdx.x*blockDim.x + threadIdx.x;
  int e = (int)(t / chunksPerE);
  long r = t - (long)e*chunksPerE;
  int lane = (int)(r & 63);
  long fb = r >> 6;
  int kb = (int)(fb % KB);
  int cb = (int)(fb / KB);
  int col = cb*32 + (lane & 31);
  int k0  = kb*32 + (lane >> 5)*16;
  const f32x4* src = (const f32x4*)(w + ((long)e*COLS + col)*K + k0);
  float s = wscl[e];
  f32x4 v0 = src[0], v1 = src[1], v2 = src[2], v3 = src[3];
  i32x4 o;
  o.x = (int)packq(v0, s, -1, 1);
  o.y = (int)packq(v1, s, -1, 1);
  o.z = (int)packq(v2, s, -1, 1);
  o.w = (int)packq(v3, s, -1, 1);
  wq[t] = o;
}

// ---------------- gather xq rows into per-expert frag-order A buffer + xrec_g ----------------
__global__ void k_gatherx(const signed char* __restrict__ xq, const int* __restrict__ tlist,
                          const int* __restrict__ cnts, const int* __restrict__ off,
                          const float* __restrict__ xrec,
                          signed char* __restrict__ xg, float* __restrict__ xrecg){
  int e = blockIdx.x & 7;
  int cnt = cnts[e];
  int w = threadIdx.x >> 6;
  int c = threadIdx.x & 63;
  int goff = off[e];
  signed char* xb = xg + (long)goff*1024;
  for (int r = (blockIdx.x>>3)*4 + w; r < cnt; r += 2048){
    int pr = tlist[e*NTOK + r];
    if (c == 0) xrecg[goff + r] = xrec[pr>>1];
    i32x4 v = *(const i32x4*)(xq + (long)(pr>>1)*DIMD + c*16);
    int kb = c>>1, lhi = c&1;
    *(i32x4*)(xb + ((long)(r>>5)*32 + kb)*1024 + (lhi*32 + (r&31))*16) = v;
  }
}

#define MF(A,B,C) C = __builtin_amdgcn_mfma_i32_32x32x32_i8(A,B,C,0,0,0)

// ---------------- GEMM1: B(32 h1 + 32 g cols) in LDS, A frag-order, row-ordered glu out ----------------
// grid 512: e = blk&7 (XCD-lock), ctile = blk>>3 (0..63). 8 waves x 64 rows = 512 rows/iter.
// (512,4): 2 blocks/CU — R14 (deep prefetch) and R16 (128KB tile) both regressed; this is the balance point.
__global__ __launch_bounds__(512, 4) void k_gemm1(
    const signed char* __restrict__ xg, const signed char* __restrict__ wqin,
    const int* __restrict__ cnts, const int* __restrict__ off,
    const float* __restrict__ xrecg_all, const float* __restrict__ wrec_in,
    unsigned short* __restrict__ glug_all)
{
  __shared__ signed char bsh[65536];
  const int e = blockIdx.x & 7;
  const int ctile = blockIdx.x >> 3;
  const int cnt = cnts[e];
  const int tid = threadIdx.x;
  const int goff = off[e];
  {
    const i32x4* s0 = (const i32x4*)(wqin + (long)e*4194304 + (long)ctile*32768);
    const i32x4* s1 = (const i32x4*)(wqin + (long)e*4194304 + (long)(64+ctile)*32768);
    i32x4* d = (i32x4*)bsh;
    #pragma unroll
    for (int i=0;i<4;++i){ d[tid + i*512] = s0[tid + i*512]; d[2048 + tid + i*512] = s1[tid + i*512]; }
  }
  __syncthreads();

  const int wave = tid>>6, lane = tid&63, l31 = lane&31, lhi = lane>>5;
  const float wr = wrec_in[e];
  const float* xrecg = xrecg_all + goff;
  unsigned short* glug = glug_all + (long)goff*HID;
  const signed char* xbase = xg + (long)goff*1024;
  const signed char* lb = bsh + lane*16;
  const int maxit = (cnt + 511) >> 9;

  #pragma unroll 1
  for (int it=0; it<maxit; ++it){
    const int rb = it*512 + wave*64;
    const i32x4* a0 = (const i32x4*)(xbase + (long)(rb>>5)*32768) + lane;
    const i32x4* a1 = a0 + 2048;

    i32x16 p0=(i32x16)0, p1=(i32x16)0, q0=(i32x16)0, q1=(i32x16)0;
    i32x4 eA0=a0[0], eA1=a1[0];
    i32x4 oA0=a0[64], oA1=a1[64];
    i32x4 eB0=*(const i32x4*)(lb),      eB1=*(const i32x4*)(lb+32768);
    i32x4 oB0=*(const i32x4*)(lb+1024), oB1=*(const i32x4*)(lb+33792);
    #pragma unroll 1
    for (int kb=0; kb<30; kb+=2){
      a0+=128; a1+=128;
      MF(eA0,eB0,p0); MF(eA1,eB0,p1); MF(eA0,eB1,q0); MF(eA1,eB1,q1);
      eA0=a0[0]; eA1=a1[0];
      eB0=*(const i32x4*)(lb + (kb+2)*1024);
      eB1=*(const i32x4*)(lb + 32768 + (kb+2)*1024);
      MF(oA0,oB0,p0); MF(oA1,oB0,p1); MF(oA0,oB1,q0); MF(oA1,oB1,q1);
      oA0=a0[64]; oA1=a1[64];
      oB0=*(const i32x4*)(lb + (kb+3)*1024);
      oB1=*(const i32x4*)(lb + 32768 + (kb+3)*1024);
    }
    MF(eA0,eB0,p0); MF(eA1,eB0,p1); MF(eA0,eB1,q0); MF(eA1,eB1,q1);
    MF(oA0,oB0,p0); MF(oA1,oB0,p1); MF(oA0,oB1,q0); MF(oA1,oB1,q1);

#define GLUEPI(P,Q,ROFF) { \
    _Pragma("unroll") \
    for (int g=0; g<16; ++g){ \
      int r = rb + ROFF + (g&3) + 8*(g>>2) + 4*lhi; \
      if (r < cnt){ \
        float dq = xrecg[r]*wr; \
        float h1 = (float)P[g]*dq; \
        float gg = (float)Q[g]*dq; \
        float t = __expf(-h1); \
        float v = h1*gg*__builtin_amdgcn_rcpf(1.f+t); \
        glug[(long)r*HID + ctile*32 + l31] = f2bf(v); \
      } \
    } }
    GLUEPI(p0,q0,0)
    GLUEPI(p1,q1,32)
#undef GLUEPI
  }
}

// ---------------- act_quant(glu row) -> hg frag-order + hrec_g (gate folded) ----------------
__global__ __launch_bounds__(256) void k_quanthg(
    const unsigned short* __restrict__ glug, const int* __restrict__ tlist,
    const int* __restrict__ cnts, const int* __restrict__ off,
    const float* __restrict__ gatep, signed char* __restrict__ hg, float* __restrict__ hrecg){
  int e = blockIdx.x & 7;
  int cnt = cnts[e];
  const int wv = threadIdx.x>>6, lane = threadIdx.x&63;
  int r = (blockIdx.x>>3)*4 + wv;
  if (r >= cnt) return;
  const int* tl = tlist + e*NTOK;
  int goff = off[e];
  signed char* hb = hg + (long)goff*2048;
  const unsigned short* row = glug + (long)(goff+r)*HID;

  u16x8 v0 = *(const u16x8*)(row + lane*8);
  u16x8 v1 = *(const u16x8*)(row + 512 + lane*8);
  u16x8 v2 = *(const u16x8*)(row + 1024 + lane*8);
  u16x8 v3 = *(const u16x8*)(row + 1536 + lane*8);
  float m = 0.f;
  #pragma unroll
  for (int j=0;j<8;++j){
    m = fmaxf(m, fmaxf(fmaxf(fabsf(bf2f(v0[j])), fabsf(bf2f(v1[j]))),
                       fmaxf(fabsf(bf2f(v2[j])), fabsf(bf2f(v3[j])))));
  }
  #pragma unroll
  for (int mm=1; mm<64; mm<<=1) m = fmaxf(m, __shfl_xor(m, mm));
  float cmm = fmaxf(m, 1e-5f);
  if (lane == 0) hrecg[goff + r] = gatep[tl[r]] * cmm * (1.f/127.f);
  float s = 127.f/cmm;

#define QCHUNK(V, CIDX) { \
    f32x4 a, b; \
    a.x=bf2f(V[0]); a.y=bf2f(V[1]); a.z=bf2f(V[2]); a.w=bf2f(V[3]); \
    b.x=bf2f(V[4]); b.y=bf2f(V[5]); b.z=bf2f(V[6]); b.w=bf2f(V[7]); \
    uint2 u; u.x = packq(a, s, -128, 127); u.y = packq(b, s, -128, 127); \
    int c = (CIDX); \
    int kb = c>>2, lhi = (c>>1)&1, h = c&1; \
    *(uint2*)(hb + ((long)(r>>5)*64 + kb)*1024 + (lhi*32 + (r&31))*16 + h*8) = u; \
  }
  QCHUNK(v0, lane)
  QCHUNK(v1, lane+64)
  QCHUNK(v2, lane+128)
  QCHUNK(v3, lane+192)
#undef QCHUNK
}

// ---------------- GEMM2: B(32 dcols) in LDS, A frag-order from hg; bf16 pout ----------------
__global__ __launch_bounds__(512, 4) void k_gemm2(
    const signed char* __restrict__ hg, const signed char* __restrict__ wqout,
    const int* __restrict__ tlist, const int* __restrict__ cnts, const int* __restrict__ off,
    const float* __restrict__ hrecg_all, const float* __restrict__ wrec_out,
    unsigned short* __restrict__ pout)
{
  __shared__ signed char bsh[65536];
  const int e = blockIdx.x & 7;
  const int j = blockIdx.x >> 3;
  const int ctile = j & 31;
  const int rh = j >> 5;
  const int cnt = cnts[e];
  const int tid = threadIdx.x;
  const int goff = off[e];
  {
    const i32x4* s0 = (const i32x4*)(wqout + (long)e*2097152 + (long)ctile*65536);
    i32x4* d = (i32x4*)bsh;
    #pragma unroll
    for (int i=0;i<8;++i) d[tid + i*512] = s0[tid + i*512];
  }
  __syncthreads();

  const int wave = tid>>6, lane = tid&63, l31 = lane&31, lhi = lane>>5;
  const int* tl = tlist + e*NTOK;
  const float wr = wrec_out[e];
  const float* hrecg = hrecg_all + goff;
  const signed char* hbase = hg + (long)goff*2048;
  const signed char* lb = bsh + lane*16;
  const int maxit = (cnt + 1023) >> 10;

  #pragma unroll 1
  for (int it=rh; it<maxit; it+=2){
    const int rb = it*1024 + wave*128;
    const i32x4* a0 = (const i32x4*)(hbase + (long)(rb>>5)*65536) + lane;
    const i32x4* a1 = a0 + 4096;
    const i32x4* a2 = a0 + 8192;
    const i32x4* a3 = a0 + 12288;

    i32x16 c0=(i32x16)0, c1=(i32x16)0, c2=(i32x16)0, c3=(i32x16)0;
    i32x4 eA0=a0[0], eA1=a1[0], eA2=a2[0], eA3=a3[0];
    i32x4 oA0=a0[64], oA1=a1[64], oA2=a2[64], oA3=a3[64];
    i32x4 eB=*(const i32x4*)(lb);
    i32x4 oB=*(const i32x4*)(lb+1024);
    #pragma unroll 1
    for (int kb=0; kb<62; kb+=2){
      a0+=128; a1+=128; a2+=128; a3+=128;
      MF(eA0,eB,c0); MF(eA1,eB,c1); MF(eA2,eB,c2); MF(eA3,eB,c3);
      eA0=a0[0]; eA1=a1[0]; eA2=a2[0]; eA3=a3[0];
      eB=*(const i32x4*)(lb + (kb+2)*1024);
      MF(oA0,oB,c0); MF(oA1,oB,c1); MF(oA2,oB,c2); MF(oA3,oB,c3);
      oA0=a0[64]; oA1=a1[64]; oA2=a2[64]; oA3=a3[64];
      oB=*(const i32x4*)(lb + (kb+3)*1024);
    }
    MF(eA0,eB,c0); MF(eA1,eB,c1); MF(eA2,eB,c2); MF(eA3,eB,c3);
    MF(oA0,oB,c0); MF(oA1,oB,c1); MF(oA2,oB,c2); MF(oA3,oB,c3);

#define OUTEPI(C,ROFF) { \
    _Pragma("unroll") \
    for (int g=0; g<16; ++g){ \
      int r = rb + ROFF + (g&3) + 8*(g>>2) + 4*lhi; \
      if (r < cnt){ \
        int pr = tl[r]; \
        float f = hrecg[r]*wr; \
        pout[(long)pr*DIMD + ctile*32 + l31] = f2bf((float)C[g]*f); \
      } \
    } }
    OUTEPI(c0,0)
    OUTEPI(c1,32)
    OUTEPI(c2,64)
    OUTEPI(c3,96)
#undef OUTEPI
  }
}

// ---------------- combine: y = bias + pout[2t] + pout[2t+1] (bf16 pout) ----------------
__global__ void k_combine(const unsigned short* __restrict__ pout, const float* __restrict__ bias,
                          float* __restrict__ y){
  long idx = (long)blockIdx.x*blockDim.x + threadIdx.x;   // over NTOK*DIMD/8
  int tok = (int)(idx >> 7);
  int c8  = (int)(idx & 127);
  u16x8 pa = ((const u16x8*)(pout + (long)tok*2*DIMD))[c8];
  u16x8 pb = ((const u16x8*)(pout + (long)tok*2*DIMD + DIMD))[c8];
  const f32x4* b4 = (const f32x4*)(bias) + c8*2;
  f32x4 b0 = b4[0], b1 = b4[1];
  f32x4 r0, r1;
  r0.x = b0.x + bf2f(pa[0]) + bf2f(pb[0]);
  r0.y = b0.y + bf2f(pa[1]) + bf2f(pb[1]);
  r0.z = b0.z + bf2f(pa[2]) + bf2f(pb[2]);
  r0.w = b0.w + bf2f(pa[3]) + bf2f(pb[3]);
  r1.x = b1.x + bf2f(pa[4]) + bf2f(pb[4]);
  r1.y = b1.y + bf2f(pa[5]) + bf2f(pb[5]);
  r1.z = b1.z + bf2f(pa[6]) + bf2f(pb[6]);
  r1.w = b1.w + bf2f(pa[7]) + bf2f(pb[7]);
  f32x4* yp = (f32x4*)(y + (long)tok*DIMD) + c8*2;
  yp[0] = r0; yp[1] = r1;
}

// ---------------- loss ----------------
__global__ void k_loss(const int* __restrict__ cnts, const float* __restrict__ psum,
                       const float* __restrict__ zsum, float* __restrict__ out){
  if (threadIdx.x==0 && blockIdx.x==0){
    float sp=0.f, sf=0.f, sw=0.f;
    for (int e=0;e<8;++e){
      float f = (float)cnts[e];
      sp += psum[e]; sf += f; sw += psum[e]*f;
    }
    float loss = 8.f*sw/(sp*sf) + 0.1f*zsum[0]/(float)NTOK;
    out[(long)NTOK*DIMD] = loss;
  }
}

extern "C" void kernel_launch(void* const* d_in, const int* in_sizes, int n_in,
                              void* d_out, int out_size, void* d_ws, size_t ws_size,
                              hipStream_t stream){
  const float* x     = (const float*)d_in[0];
  const float* wg    = (const float*)d_in[1];
  const float* w_in  = (const float*)d_in[2];
  const float* w_out = (const float*)d_in[3];
  const float* bias  = (const float*)d_in[4];
  float* y = (float*)d_out;
  char* ws = (char*)d_ws;

  signed char* xq    = (signed char*)(ws + XQ_OFF);
  signed char* wqin  = (signed char*)(ws + WQIN_OFF);
  signed char* wqout = (signed char*)(ws + WQOUT_OFF);
  signed char* xg    = (signed char*)(ws + XG_OFF);
  signed char* hg    = (signed char*)(ws + HG_OFF);
  unsigned short* glug = (unsigned short*)(ws + GLUG_OFF);
  unsigned short* pout = (unsigned short*)(ws + GLUG_OFF);  // reuse: glug dead after k_quanthg
  float* xrecg = (float*)(ws + XRECG_OFF);
  float* gatep = (float*)(ws + GATE_OFF);
  float* hrecg = (float*)(ws + HRECG_OFF);
  int* tlist = (int*)(ws + TLIST_OFF);
  int* cnts  = (int*)(ws + CNT_OFF);
  float* psum = (float*)(ws + PSUM_OFF);
  float* zsum = (float*)(ws + ZSUM_OFF);
  float* part = (float*)(ws + PART_OFF);
  float* wrec_in  = (float*)(ws + WRECIN_OFF);
  float* wrec_out = (float*)(ws + WRECOUT_OFF);
  float* wscl_in  = (float*)(ws + WSCLIN_OFF);
  float* wscl_out = (float*)(ws + WSCLOUT_OFF);
  int* offe = (int*)(ws + OFF_OFF);

  // token-indexed xrec lives in the HRECG region early (hrecg proper is written later by k_quanthg,
  // after k_gatherx has consumed xrec -> safe temporal reuse).
  float* xrec = (float*)(ws + HRECG_OFF);

  k_init  <<<1, 64, 0, stream>>>(cnts, psum, zsum);
  k_router<<<512, 1024, 0, stream>>>(x, wg, xq, xrec, gatep, tlist, cnts, psum, zsum);
  k_wabs  <<<768, 256, 0, stream>>>(w_in, w_out, part);
  k_wmean <<<1, 64, 0, stream>>>(part, cnts, wrec_in, wrec_out, wscl_in, wscl_out, offe);
  k_packw <<<8192, 256, 0, stream>>>(w_in,  (i32x4*)wqin,  wscl_in,  4096, 1024, 32, 262144L);
  k_packw <<<4096, 256, 0, stream>>>(w_out, (i32x4*)wqout, wscl_out, 1024, 2048, 64, 131072L);
  k_gatherx<<<4096, 256, 0, stream>>>(xq, tlist, cnts, offe, xrec, xg, xrecg);
  k_gemm1 <<<512, 512, 0, stream>>>(xg, wqin, cnts, offe, xrecg, wrec_in, glug);
  k_quanthg<<<16384, 256, 0, stream>>>(glug, tlist, cnts, offe, gatep, hg, hrecg);
  k_gemm2 <<<512, 512, 0, stream>>>(hg, wqout, tlist, cnts, offe, hrecg, wrec_out, pout);
  k_combine<<<4096, 256, 0, stream>>>(pout, bias, y);
  k_loss  <<<1, 64, 0, stream>>>(cnts, psum, zsum, y);
}